// Round 9
// baseline (170.721 us; speedup 1.0000x reference)
//
#include <hip/hip_runtime.h>
#include <math.h>

// TSC (order-3) particle-to-mesh deposition.
//
// Fast path (C==8, n%4==0, n<=256): per-1x1-column capped bin lists of
// PACKED 48B records (one atomicAdd fill kernel), then a pure-streaming
// REGISTER GATHER: one wave per (x,y) column, lane owns 4 z-cells with
// acc[4][8] in VGPRs. The wave walks its 9 neighbor bins (wave-uniform ->
// broadcast loads, no divergence, no LDS, no barriers, no atomics) and
// writes the column once with nontemporal float4 stores (contiguous per
// wave-instruction, consecutive blocks = consecutive y -> sequential
// streams). Structurally identical to the r0 transpose kernel that
// sustained ~4.8 TB/s -- eliminates every suspect of the ~1.7 TB/s wall
// that all LDS-tile designs (r1/r3/r4/r6/r7/r8) hit.
//
// Fallbacks: interleaved-atomic two-phase (C==8), generic planar atomics.

#define KColCAP 16   // records per 1x1 column bin (lambda ~2.5)

typedef float nfloat4 __attribute__((ext_vector_type(4)));

// TSC weight for axis offset o in {-1,0,+1} at fractional distance d in [-0.5,0.5]
__device__ __forceinline__ float tsc_w(int o, float d) {
    float t = 0.5f + (float)o * d;
    return (o == 0) ? (0.75f - d * d) : (0.5f * t * t);
}

__device__ __forceinline__ float inv_spacing(const float* __restrict__ cell, int n) {
    float tr = cell[0] + cell[4] + cell[8];
    return (3.0f * (float)n) / tr;
}

// ---------------- binning: packed records into 1x1-column lists ----------------

__global__ __launch_bounds__(256) void fill_recs(
    const float* __restrict__ pos, const float* __restrict__ cell,
    const float* __restrict__ emb,
    int* __restrict__ counts, int* __restrict__ ovf_cnt,
    float4* __restrict__ binrec, int* __restrict__ ovf,
    int N, int n)
{
    int i = blockIdx.x * blockDim.x + threadIdx.x;
    if (i >= N) return;
    float inv_sp = inv_spacing(cell, n);
    float px = pos[3 * i + 0] * inv_sp;
    float py = pos[3 * i + 1] * inv_sp;
    float pz = pos[3 * i + 2] * inv_sp;
    int cx = (int)rintf(px); if (cx >= n) cx -= n; else if (cx < 0) cx += n;
    int cy = (int)rintf(py); if (cy >= n) cy -= n; else if (cy < 0) cy += n;
    int bin = cx * n + cy;
    int slot = atomicAdd(&counts[bin], 1);
    if (slot < KColCAP) {
        const float4* e4 = (const float4*)(emb + (size_t)i * 8);
        float4* r = binrec + (size_t)(bin * KColCAP + slot) * 3;
        r[0] = make_float4(px, py, pz, 0.0f);
        r[1] = e4[0];
        r[2] = e4[1];
    } else {
        int o = atomicAdd(ovf_cnt, 1);
        ovf[o] = i;   // ovf sized N: cannot overflow
    }
}

// ---------------- register-gather: one wave per column ----------------
// grid = (n/4, n): blockIdx.x -> y-group (4 y's per 256-thread block),
// blockIdx.y -> x. Wave w handles column (x, y0+w); lane l owns z 4l..4l+3.

__global__ __launch_bounds__(256) void gather_col(
    const float4* __restrict__ binrec, const int* __restrict__ counts,
    float* __restrict__ out, int n, int nzc)
{
    const int lane = threadIdx.x & 63;
    const int y = blockIdx.x * 4 + (threadIdx.x >> 6);
    const int x = blockIdx.y;
    if (lane >= nzc) return;
    const int z0 = lane * 4;
    const int half = n >> 1;

    // prefetch the 9 neighbor-bin counts/bases (static unrolled -> registers)
    int cnt[3][3], cb[3][3];
    #pragma unroll
    for (int jx = 0; jx < 3; ++jx) {
        int xb = x + jx - 1; if (xb < 0) xb += n; else if (xb >= n) xb -= n;
        #pragma unroll
        for (int jy = 0; jy < 3; ++jy) {
            int yb = y + jy - 1; if (yb < 0) yb += n; else if (yb >= n) yb -= n;
            int bin = xb * n + yb;
            cb[jx][jy] = bin * KColCAP;
            int c = counts[bin];
            cnt[jx][jy] = (c < KColCAP) ? c : KColCAP;
        }
    }

    float acc[4][8];
    #pragma unroll
    for (int zk = 0; zk < 4; ++zk)
        #pragma unroll
        for (int ch = 0; ch < 8; ++ch) acc[zk][ch] = 0.0f;

    #pragma unroll
    for (int jx = 0; jx < 3; ++jx) {
        #pragma unroll
        for (int jy = 0; jy < 3; ++jy) {
            const int c = cnt[jx][jy];
            const float4* rb = binrec + (size_t)cb[jx][jy] * 3;
            for (int s = 0; s < c; ++s) {
                float4 P  = rb[3 * s + 0];
                float4 e0 = rb[3 * s + 1];
                float4 e1 = rb[3 * s + 2];

                float cxf = rintf(P.x); float dx = P.x - cxf;
                float cyf = rintf(P.y); float dy = P.y - cyf;
                float czf = rintf(P.z); float dz = P.z - czf;
                int cz = (int)czf; if (cz >= n) cz -= n; else if (cz < 0) cz += n;

                // output-cell offset from atom center: o = 1 - jx (exact, bins
                // are the atom's own column +-1)
                float tx = 0.5f + (float)(1 - jx) * dx;
                float wx = (jx == 1) ? (0.75f - dx * dx) : (0.5f * tx * tx);
                float ty = 0.5f + (float)(1 - jy) * dy;
                float wy = (jy == 1) ? (0.75f - dy * dy) : (0.5f * ty * ty);
                float wxy = wx * wy;

                #pragma unroll
                for (int zk = 0; zk < 4; ++zk) {
                    int dzi = z0 + zk - cz;
                    if (dzi > half) dzi -= n; else if (dzi < -half) dzi += n;
                    float fd = (float)dzi;
                    float t = 0.5f + fd * dz;
                    float wz = (dzi == 0) ? (0.75f - dz * dz) : (0.5f * t * t);
                    float w = (fabsf(fd) <= 1.0f) ? wxy * wz : 0.0f;
                    acc[zk][0] += w * e0.x;
                    acc[zk][1] += w * e0.y;
                    acc[zk][2] += w * e0.z;
                    acc[zk][3] += w * e0.w;
                    acc[zk][4] += w * e1.x;
                    acc[zk][5] += w * e1.y;
                    acc[zk][6] += w * e1.z;
                    acc[zk][7] += w * e1.w;
                }
            }
        }
    }

    // writeout: one nontemporal float4 per channel (z0 % 4 == 0 -> aligned).
    const size_t n3 = (size_t)n * n * n;
    const size_t colbase = ((size_t)x * n + y) * (size_t)n + z0;
    #pragma unroll
    for (int ch = 0; ch < 8; ++ch) {
        nfloat4 v = { acc[0][ch], acc[1][ch], acc[2][ch], acc[3][ch] };
        __builtin_nontemporal_store(v, (nfloat4*)(out + (size_t)ch * n3 + colbase));
    }
}

// overflow cleanup: global planar atomics for atoms that missed their bin list
__global__ __launch_bounds__(256) void deposit_overflow(
    const float* __restrict__ pos, const float* __restrict__ cell,
    const float* __restrict__ emb, const int* __restrict__ ovf_cnt,
    const int* __restrict__ ovf, float* __restrict__ out, int n)
{
    int m = *ovf_cnt;
    int i = blockIdx.x * blockDim.x + threadIdx.x;
    if (i >= m) return;
    int ai = ovf[i];
    float inv_sp = inv_spacing(cell, n);
    float p[3], d[3]; int c0[3];
    #pragma unroll
    for (int kk = 0; kk < 3; ++kk) {
        p[kk] = pos[3 * ai + kk] * inv_sp;
        c0[kk] = (int)rintf(p[kk]);
        d[kk] = p[kk] - (float)c0[kk];
    }
    float w[3][3];
    #pragma unroll
    for (int kk = 0; kk < 3; ++kk) {
        float dd = d[kk];
        w[kk][0] = tsc_w(-1, dd); w[kk][1] = tsc_w(0, dd); w[kk][2] = tsc_w(1, dd);
    }
    int W[3][3];
    #pragma unroll
    for (int kk = 0; kk < 3; ++kk)
        #pragma unroll
        for (int a = 0; a < 3; ++a) {
            int v = c0[kk] - 1 + a; if (v < 0) v += n; else if (v >= n) v -= n;
            W[kk][a] = v;
        }
    size_t n3 = (size_t)n * n * n;
    const float4* e4 = (const float4*)(emb + (size_t)ai * 8);
    float4 e0 = e4[0], e1 = e4[1];
    float e[8] = {e0.x, e0.y, e0.z, e0.w, e1.x, e1.y, e1.z, e1.w};
    for (int a = 0; a < 3; ++a)
        for (int bq = 0; bq < 3; ++bq)
            for (int cq = 0; cq < 3; ++cq) {
                float wt = w[0][a] * w[1][bq] * w[2][cq];
                size_t g = ((size_t)W[0][a] * n + W[1][bq]) * n + W[2][cq];
                #pragma unroll
                for (int ch = 0; ch < 8; ++ch)
                    atomicAdd(out + (size_t)ch * n3 + g, wt * e[ch]);
            }
}

// ---------------- fallback: interleaved atomics + transpose ----------------

__global__ __launch_bounds__(256) void deposit_tsc8_ilv(
    const float* __restrict__ pos,
    const float* __restrict__ cell,
    const float* __restrict__ emb,
    float* __restrict__ ws,
    int total, int n)
{
    int t = blockIdx.x * blockDim.x + threadIdx.x;
    if (t >= total) return;
    int atom = t / 27;
    int c    = t - atom * 27;
    int a    = c / 9;
    int rem  = c - a * 9;
    int b    = rem / 3;
    int cc   = rem - b * 3;

    float inv_sp = inv_spacing(cell, n);

    float px = pos[3 * atom + 0] * inv_sp;
    float py = pos[3 * atom + 1] * inv_sp;
    float pz = pos[3 * atom + 2] * inv_sp;

    int cx = (int)rintf(px);  float dx = px - (float)cx;
    int cy = (int)rintf(py);  float dy = py - (float)cy;
    int cz = (int)rintf(pz);  float dz = pz - (float)cz;

    float w = tsc_w(a - 1, dx) * tsc_w(b - 1, dy) * tsc_w(cc - 1, dz);

    int x = cx - 1 + a;  if (x < 0) x += n; else if (x >= n) x -= n;
    int y = cy - 1 + b;  if (y < 0) y += n; else if (y >= n) y -= n;
    int z = cz - 1 + cc; if (z < 0) z += n; else if (z >= n) z -= n;

    const float4* e4 = (const float4*)(emb + (size_t)atom * 8);
    float4 e0 = e4[0], e1 = e4[1];

    float* p = ws + ((size_t)((x * n + y) * n + z)) * 8;
    atomicAdd(p + 0, w * e0.x);
    atomicAdd(p + 1, w * e0.y);
    atomicAdd(p + 2, w * e0.z);
    atomicAdd(p + 3, w * e0.w);
    atomicAdd(p + 4, w * e1.x);
    atomicAdd(p + 5, w * e1.y);
    atomicAdd(p + 6, w * e1.z);
    atomicAdd(p + 7, w * e1.w);
}

__global__ __launch_bounds__(256) void transpose_ilv8(
    const float* __restrict__ ws, float* __restrict__ out, int n3)
{
    int t = blockIdx.x * blockDim.x + threadIdx.x;
    int g0 = t * 4;
    if (g0 >= n3) return;
    const float4* w4 = (const float4*)(ws + (size_t)g0 * 8);
    float4 r0 = w4[0], r1 = w4[1];
    float4 r2 = w4[2], r3 = w4[3];
    float4 r4 = w4[4], r5 = w4[5];
    float4 r6 = w4[6], r7 = w4[7];

    *(float4*)(out + (size_t)0 * n3 + g0) = make_float4(r0.x, r2.x, r4.x, r6.x);
    *(float4*)(out + (size_t)1 * n3 + g0) = make_float4(r0.y, r2.y, r4.y, r6.y);
    *(float4*)(out + (size_t)2 * n3 + g0) = make_float4(r0.z, r2.z, r4.z, r6.z);
    *(float4*)(out + (size_t)3 * n3 + g0) = make_float4(r0.w, r2.w, r4.w, r6.w);
    *(float4*)(out + (size_t)4 * n3 + g0) = make_float4(r1.x, r3.x, r5.x, r7.x);
    *(float4*)(out + (size_t)5 * n3 + g0) = make_float4(r1.y, r3.y, r5.y, r7.y);
    *(float4*)(out + (size_t)6 * n3 + g0) = make_float4(r1.z, r3.z, r5.z, r7.z);
    *(float4*)(out + (size_t)7 * n3 + g0) = make_float4(r1.w, r3.w, r5.w, r7.w);
}

// ---------------- fallback: generic planar atomics ----------------

__global__ __launch_bounds__(256) void deposit_tsc_gen(
    const float* __restrict__ pos,
    const float* __restrict__ cell,
    const float* __restrict__ emb,
    float* __restrict__ out,
    int N, int n, int C)
{
    int i = blockIdx.x * blockDim.x + threadIdx.x;
    if (i >= N) return;

    float inv_sp = inv_spacing(cell, n);

    float p[3], d[3];
    int c0[3];
    #pragma unroll
    for (int k = 0; k < 3; ++k) {
        p[k] = pos[3 * i + k] * inv_sp;
        c0[k] = (int)rintf(p[k]);
        d[k] = p[k] - (float)c0[k];
    }
    float w[3][3];
    #pragma unroll
    for (int k = 0; k < 3; ++k) {
        float dd = d[k], d2 = dd * dd;
        w[k][0] = 0.125f * (1.0f - 4.0f * dd + 4.0f * d2);
        w[k][1] = 0.25f  * (3.0f - 4.0f * d2);
        w[k][2] = 0.125f * (1.0f + 4.0f * dd + 4.0f * d2);
    }
    int W[3][3];
    #pragma unroll
    for (int k = 0; k < 3; ++k) {
        #pragma unroll
        for (int a = 0; a < 3; ++a) {
            int v = c0[k] - 1 + a; if (v < 0) v += n; else if (v >= n) v -= n;
            W[k][a] = v;
        }
    }
    int n3 = n * n * n;
    for (int a = 0; a < 3; ++a)
        for (int b = 0; b < 3; ++b)
            for (int cc = 0; cc < 3; ++cc) {
                float wt = w[0][a] * w[1][b] * w[2][cc];
                int g = (W[0][a] * n + W[1][b]) * n + W[2][cc];
                for (int ch = 0; ch < C; ++ch)
                    atomicAdd(out + (size_t)ch * n3 + g, wt * emb[(size_t)i * C + ch]);
            }
}

extern "C" void kernel_launch(void* const* d_in, const int* in_sizes, int n_in,
                              void* d_out, int out_size, void* d_ws, size_t ws_size,
                              hipStream_t stream) {
    const float* pos  = (const float*)d_in[0];
    const float* cell = (const float*)d_in[1];
    const float* emb  = (const float*)d_in[2];
    float* out = (float*)d_out;
    float* ws  = (float*)d_ws;

    int N = in_sizes[0] / 3;
    int C = in_sizes[2] / N;
    long long n3l = (long long)out_size / C;
    int n = (int)llroundf(cbrtf((float)n3l));
    int n3 = (int)n3l;

    int block = 256;

    // ---- register-gather fast path ----
    {
        int nb = n * n;
        size_t rec_off = (((size_t)nb + 4 + (size_t)N) * sizeof(int) + 15) & ~(size_t)15;
        size_t need = rec_off + (size_t)nb * KColCAP * 48;
        bool ok = (C == 8) && (n % 4 == 0) && n >= 8 && n <= 256
                  && ws_size >= need
                  && ((long long)n * n * n == n3l);
        if (ok) {
            int* counts  = (int*)d_ws;
            int* ovf_cnt = counts + nb;
            int* ovf     = counts + nb + 4;
            float4* binrec = (float4*)((char*)d_ws + rec_off);

            (void)hipMemsetAsync(counts, 0, (size_t)(nb + 4) * sizeof(int), stream);
            fill_recs<<<(N + block - 1) / block, block, 0, stream>>>(
                pos, cell, emb, counts, ovf_cnt, binrec, ovf, N, n);

            dim3 grid(n / 4, n);
            gather_col<<<grid, block, 0, stream>>>(
                binrec, counts, out, n, n / 4);

            deposit_overflow<<<(N + block - 1) / block, block, 0, stream>>>(
                pos, cell, emb, ovf_cnt, ovf, out, n);
            return;
        }
    }

    // ---- fallback: interleaved atomics + transpose ----
    size_t need = (size_t)out_size * sizeof(float);
    if (C == 8 && ws_size >= need && (n3 % 4) == 0) {
        (void)hipMemsetAsync(d_ws, 0, need, stream);
        int total = N * 27;
        deposit_tsc8_ilv<<<(total + block - 1) / block, block, 0, stream>>>(
            pos, cell, emb, ws, total, n);
        int tthreads = n3 / 4;
        transpose_ilv8<<<(tthreads + block - 1) / block, block, 0, stream>>>(
            ws, out, n3);
    } else {
        (void)hipMemsetAsync(d_out, 0, (size_t)out_size * sizeof(float), stream);
        int grid = (N + block - 1) / block;
        deposit_tsc_gen<<<grid, block, 0, stream>>>(pos, cell, emb, out, N, n, C);
    }
}

// Round 10
// 145.910 us; speedup vs baseline: 1.1700x; 1.1700x over previous
//
#include <hip/hip_runtime.h>
#include <math.h>

// TSC (order-3) particle-to-mesh deposition.
//
// Fast path (C==8, n%4==0, n<=256): per-1x1-column capped bin lists of
// PACKED 48B records, then WAVE-SCATTER-GATHER: one wave per (x,y) column.
// r9's broadcast gather was 96% VALUBusy with >97% of FMAs computing w=0
// (every atom evaluated at every z-cell). Here lanes are packed onto useful
// work: per round, lane = (atom-slot s<21, z-corner zc in {-1,0,1}); each
// lane decodes its atom once (single wxy per atom -- the column fixes the
// xy corner), computes one wz, and issues 8 ds_add_f32 into the wave's
// PRIVATE LDS column [8ch][n] (channel stride folded into the ds offset
// immediate). ~200 wave-insts/column vs r9's ~1900. One barrier, then the
// same streaming nontemporal float4 writeout as r9.
//
// Fallbacks: interleaved-atomic two-phase (C==8), generic planar atomics.

#define KColCAP 16   // records per 1x1 column bin (lambda ~2.5)

typedef float nfloat4 __attribute__((ext_vector_type(4)));

// TSC weight for axis offset o in {-1,0,+1} at fractional distance d in [-0.5,0.5]
__device__ __forceinline__ float tsc_w(int o, float d) {
    float t = 0.5f + (float)o * d;
    return (o == 0) ? (0.75f - d * d) : (0.5f * t * t);
}

__device__ __forceinline__ float inv_spacing(const float* __restrict__ cell, int n) {
    float tr = cell[0] + cell[4] + cell[8];
    return (3.0f * (float)n) / tr;
}

// ---------------- binning: packed records into 1x1-column lists ----------------

__global__ __launch_bounds__(256) void fill_recs(
    const float* __restrict__ pos, const float* __restrict__ cell,
    const float* __restrict__ emb,
    int* __restrict__ counts, int* __restrict__ ovf_cnt,
    float4* __restrict__ binrec, int* __restrict__ ovf,
    int N, int n)
{
    int i = blockIdx.x * blockDim.x + threadIdx.x;
    if (i >= N) return;
    float inv_sp = inv_spacing(cell, n);
    float px = pos[3 * i + 0] * inv_sp;
    float py = pos[3 * i + 1] * inv_sp;
    float pz = pos[3 * i + 2] * inv_sp;
    int cx = (int)rintf(px); if (cx >= n) cx -= n; else if (cx < 0) cx += n;
    int cy = (int)rintf(py); if (cy >= n) cy -= n; else if (cy < 0) cy += n;
    int bin = cx * n + cy;
    int slot = atomicAdd(&counts[bin], 1);
    if (slot < KColCAP) {
        const float4* e4 = (const float4*)(emb + (size_t)i * 8);
        float4* r = binrec + (size_t)(bin * KColCAP + slot) * 3;
        r[0] = make_float4(px, py, pz, 0.0f);
        r[1] = e4[0];
        r[2] = e4[1];
    } else {
        int o = atomicAdd(ovf_cnt, 1);
        ovf[o] = i;   // ovf sized N: cannot overflow
    }
}

// ---------------- wave-scatter gather: one wave per column ----------------
// grid = (n/4, n): blockIdx.x -> y-group (4 waves per block), blockIdx.y -> x.
// LDS: per wave private column [8ch][n] floats (block total 32n floats).

__global__ __launch_bounds__(256) void gather_scatter(
    const float4* __restrict__ binrec, const int* __restrict__ counts,
    float* __restrict__ out, int n)
{
    extern __shared__ float lds[];
    const int tid = threadIdx.x;
    const int lane = tid & 63;
    const int wv = tid >> 6;
    const int y = blockIdx.x * 4 + wv;
    const int x = blockIdx.y;
    float* col = lds + wv * 8 * n;     // [8][n]

    // zero this wave's column (8n floats = 2n float4)
    {
        nfloat4* c4 = (nfloat4*)col;
        const int z4 = 2 * n;
        for (int i = lane; i < z4; i += 64)
            c4[i] = (nfloat4)(0.f);
    }

    // 9 neighbor-bin meta in registers (wave-uniform broadcast loads)
    int base[9], pref[10];
    pref[0] = 0;
    #pragma unroll
    for (int j = 0; j < 9; ++j) {
        int jx = j / 3, jy = j - 3 * (j / 3);       // compile-time per j
        int xb = x + jx - 1; if (xb < 0) xb += n; else if (xb >= n) xb -= n;
        int yb = y + jy - 1; if (yb < 0) yb += n; else if (yb >= n) yb -= n;
        int bin = xb * n + yb;
        base[j] = bin * KColCAP;
        int c = counts[bin];
        c = (c < KColCAP) ? c : KColCAP;
        pref[j + 1] = pref[j] + c;
    }
    const int tot = pref[9];

    // lane = (atom slot s, z-corner zc)
    const int s  = lane / 3;           // 0..21 (lane 63 -> s=21, inactive)
    const int zc = lane - 3 * s - 1;   // -1, 0, +1

    for (int q0 = 0; q0 < tot; q0 += 21) {
        const int q = q0 + s;
        if (s < 21 && q < tot) {
            // select bin j and record index via unrolled cndmask chain
            int rec = base[0] + q;
            int jxv = 0, jyv = 0;
            #pragma unroll
            for (int k = 1; k < 9; ++k) {
                bool ge = (q >= pref[k]);
                int cand = base[k] + (q - pref[k]);
                rec = ge ? cand : rec;
                jxv = ge ? (k / 3) : jxv;            // constants: k/3, k%3
                jyv = ge ? (k - 3 * (k / 3)) : jyv;
            }
            const float4* rp = binrec + (size_t)rec * 3;
            float4 P  = rp[0];
            float4 e0 = rp[1];
            float4 e1 = rp[2];

            float cxf = rintf(P.x); float dx = P.x - cxf;
            float cyf = rintf(P.y); float dy = P.y - cyf;
            float czf = rintf(P.z); float dz = P.z - czf;

            // xy corner weight: cell offset o = 1 - j (exact by bin construction)
            float tx = 0.5f + (float)(1 - jxv) * dx;
            float wx = (jxv == 1) ? (0.75f - dx * dx) : (0.5f * tx * tx);
            float ty = 0.5f + (float)(1 - jyv) * dy;
            float wy = (jyv == 1) ? (0.75f - dy * dy) : (0.5f * ty * ty);
            float tz = 0.5f + (float)zc * dz;
            float wz = (zc == 0) ? (0.75f - dz * dz) : (0.5f * tz * tz);
            float w = wx * wy * wz;

            int cz = (int)czf; if (cz >= n) cz -= n; else if (cz < 0) cz += n;
            int z = cz + zc; if (z < 0) z += n; else if (z >= n) z -= n;

            float* p = col + z;                       // ch stride n (imm offset)
            atomicAdd(p + 0 * n, w * e0.x);
            atomicAdd(p + 1 * n, w * e0.y);
            atomicAdd(p + 2 * n, w * e0.z);
            atomicAdd(p + 3 * n, w * e0.w);
            atomicAdd(p + 4 * n, w * e1.x);
            atomicAdd(p + 5 * n, w * e1.y);
            atomicAdd(p + 6 * n, w * e1.z);
            atomicAdd(p + 7 * n, w * e1.w);
        }
    }
    __syncthreads();

    // writeout: per channel one nontemporal float4 per lane (z = 4*lane..+3)
    const int z0 = lane * 4;
    if (z0 < n) {
        const size_t n3 = (size_t)n * n * n;
        const size_t colbase = ((size_t)x * n + y) * (size_t)n + z0;
        #pragma unroll
        for (int ch = 0; ch < 8; ++ch) {
            nfloat4 v = *(const nfloat4*)(col + ch * n + z0);
            __builtin_nontemporal_store(v, (nfloat4*)(out + (size_t)ch * n3 + colbase));
        }
    }
}

// overflow cleanup: global planar atomics for atoms that missed their bin list
__global__ __launch_bounds__(256) void deposit_overflow(
    const float* __restrict__ pos, const float* __restrict__ cell,
    const float* __restrict__ emb, const int* __restrict__ ovf_cnt,
    const int* __restrict__ ovf, float* __restrict__ out, int n)
{
    int m = *ovf_cnt;
    int i = blockIdx.x * blockDim.x + threadIdx.x;
    if (i >= m) return;
    int ai = ovf[i];
    float inv_sp = inv_spacing(cell, n);
    float p[3], d[3]; int c0[3];
    #pragma unroll
    for (int kk = 0; kk < 3; ++kk) {
        p[kk] = pos[3 * ai + kk] * inv_sp;
        c0[kk] = (int)rintf(p[kk]);
        d[kk] = p[kk] - (float)c0[kk];
    }
    float w[3][3];
    #pragma unroll
    for (int kk = 0; kk < 3; ++kk) {
        float dd = d[kk];
        w[kk][0] = tsc_w(-1, dd); w[kk][1] = tsc_w(0, dd); w[kk][2] = tsc_w(1, dd);
    }
    int W[3][3];
    #pragma unroll
    for (int kk = 0; kk < 3; ++kk)
        #pragma unroll
        for (int a = 0; a < 3; ++a) {
            int v = c0[kk] - 1 + a; if (v < 0) v += n; else if (v >= n) v -= n;
            W[kk][a] = v;
        }
    size_t n3 = (size_t)n * n * n;
    const float4* e4 = (const float4*)(emb + (size_t)ai * 8);
    float4 e0 = e4[0], e1 = e4[1];
    float e[8] = {e0.x, e0.y, e0.z, e0.w, e1.x, e1.y, e1.z, e1.w};
    for (int a = 0; a < 3; ++a)
        for (int bq = 0; bq < 3; ++bq)
            for (int cq = 0; cq < 3; ++cq) {
                float wt = w[0][a] * w[1][bq] * w[2][cq];
                size_t g = ((size_t)W[0][a] * n + W[1][bq]) * n + W[2][cq];
                #pragma unroll
                for (int ch = 0; ch < 8; ++ch)
                    atomicAdd(out + (size_t)ch * n3 + g, wt * e[ch]);
            }
}

// ---------------- fallback: interleaved atomics + transpose ----------------

__global__ __launch_bounds__(256) void deposit_tsc8_ilv(
    const float* __restrict__ pos,
    const float* __restrict__ cell,
    const float* __restrict__ emb,
    float* __restrict__ ws,
    int total, int n)
{
    int t = blockIdx.x * blockDim.x + threadIdx.x;
    if (t >= total) return;
    int atom = t / 27;
    int c    = t - atom * 27;
    int a    = c / 9;
    int rem  = c - a * 9;
    int b    = rem / 3;
    int cc   = rem - b * 3;

    float inv_sp = inv_spacing(cell, n);

    float px = pos[3 * atom + 0] * inv_sp;
    float py = pos[3 * atom + 1] * inv_sp;
    float pz = pos[3 * atom + 2] * inv_sp;

    int cx = (int)rintf(px);  float dx = px - (float)cx;
    int cy = (int)rintf(py);  float dy = py - (float)cy;
    int cz = (int)rintf(pz);  float dz = pz - (float)cz;

    float w = tsc_w(a - 1, dx) * tsc_w(b - 1, dy) * tsc_w(cc - 1, dz);

    int x = cx - 1 + a;  if (x < 0) x += n; else if (x >= n) x -= n;
    int y = cy - 1 + b;  if (y < 0) y += n; else if (y >= n) y -= n;
    int z = cz - 1 + cc; if (z < 0) z += n; else if (z >= n) z -= n;

    const float4* e4 = (const float4*)(emb + (size_t)atom * 8);
    float4 e0 = e4[0], e1 = e4[1];

    float* p = ws + ((size_t)((x * n + y) * n + z)) * 8;
    atomicAdd(p + 0, w * e0.x);
    atomicAdd(p + 1, w * e0.y);
    atomicAdd(p + 2, w * e0.z);
    atomicAdd(p + 3, w * e0.w);
    atomicAdd(p + 4, w * e1.x);
    atomicAdd(p + 5, w * e1.y);
    atomicAdd(p + 6, w * e1.z);
    atomicAdd(p + 7, w * e1.w);
}

__global__ __launch_bounds__(256) void transpose_ilv8(
    const float* __restrict__ ws, float* __restrict__ out, int n3)
{
    int t = blockIdx.x * blockDim.x + threadIdx.x;
    int g0 = t * 4;
    if (g0 >= n3) return;
    const float4* w4 = (const float4*)(ws + (size_t)g0 * 8);
    float4 r0 = w4[0], r1 = w4[1];
    float4 r2 = w4[2], r3 = w4[3];
    float4 r4 = w4[4], r5 = w4[5];
    float4 r6 = w4[6], r7 = w4[7];

    *(float4*)(out + (size_t)0 * n3 + g0) = make_float4(r0.x, r2.x, r4.x, r6.x);
    *(float4*)(out + (size_t)1 * n3 + g0) = make_float4(r0.y, r2.y, r4.y, r6.y);
    *(float4*)(out + (size_t)2 * n3 + g0) = make_float4(r0.z, r2.z, r4.z, r6.z);
    *(float4*)(out + (size_t)3 * n3 + g0) = make_float4(r0.w, r2.w, r4.w, r6.w);
    *(float4*)(out + (size_t)4 * n3 + g0) = make_float4(r1.x, r3.x, r5.x, r7.x);
    *(float4*)(out + (size_t)5 * n3 + g0) = make_float4(r1.y, r3.y, r5.y, r7.y);
    *(float4*)(out + (size_t)6 * n3 + g0) = make_float4(r1.z, r3.z, r5.z, r7.z);
    *(float4*)(out + (size_t)7 * n3 + g0) = make_float4(r1.w, r3.w, r5.w, r7.w);
}

// ---------------- fallback: generic planar atomics ----------------

__global__ __launch_bounds__(256) void deposit_tsc_gen(
    const float* __restrict__ pos,
    const float* __restrict__ cell,
    const float* __restrict__ emb,
    float* __restrict__ out,
    int N, int n, int C)
{
    int i = blockIdx.x * blockDim.x + threadIdx.x;
    if (i >= N) return;

    float inv_sp = inv_spacing(cell, n);

    float p[3], d[3];
    int c0[3];
    #pragma unroll
    for (int k = 0; k < 3; ++k) {
        p[k] = pos[3 * i + k] * inv_sp;
        c0[k] = (int)rintf(p[k]);
        d[k] = p[k] - (float)c0[k];
    }
    float w[3][3];
    #pragma unroll
    for (int k = 0; k < 3; ++k) {
        float dd = d[k], d2 = dd * dd;
        w[k][0] = 0.125f * (1.0f - 4.0f * dd + 4.0f * d2);
        w[k][1] = 0.25f  * (3.0f - 4.0f * d2);
        w[k][2] = 0.125f * (1.0f + 4.0f * dd + 4.0f * d2);
    }
    int W[3][3];
    #pragma unroll
    for (int k = 0; k < 3; ++k) {
        #pragma unroll
        for (int a = 0; a < 3; ++a) {
            int v = c0[k] - 1 + a; if (v < 0) v += n; else if (v >= n) v -= n;
            W[k][a] = v;
        }
    }
    int n3 = n * n * n;
    for (int a = 0; a < 3; ++a)
        for (int b = 0; b < 3; ++b)
            for (int cc = 0; cc < 3; ++cc) {
                float wt = w[0][a] * w[1][b] * w[2][cc];
                int g = (W[0][a] * n + W[1][b]) * n + W[2][cc];
                for (int ch = 0; ch < C; ++ch)
                    atomicAdd(out + (size_t)ch * n3 + g, wt * emb[(size_t)i * C + ch]);
            }
}

extern "C" void kernel_launch(void* const* d_in, const int* in_sizes, int n_in,
                              void* d_out, int out_size, void* d_ws, size_t ws_size,
                              hipStream_t stream) {
    const float* pos  = (const float*)d_in[0];
    const float* cell = (const float*)d_in[1];
    const float* emb  = (const float*)d_in[2];
    float* out = (float*)d_out;
    float* ws  = (float*)d_ws;

    int N = in_sizes[0] / 3;
    int C = in_sizes[2] / N;
    long long n3l = (long long)out_size / C;
    int n = (int)llroundf(cbrtf((float)n3l));
    int n3 = (int)n3l;

    int block = 256;

    // ---- wave-scatter fast path ----
    {
        int nb = n * n;
        size_t lds_bytes = (size_t)4 * 8 * n * sizeof(float);   // 128n B
        size_t rec_off = (((size_t)nb + 4 + (size_t)N) * sizeof(int) + 15) & ~(size_t)15;
        size_t need = rec_off + (size_t)nb * KColCAP * 48;
        bool ok = (C == 8) && (n % 4 == 0) && n >= 8 && n <= 256
                  && lds_bytes <= 64 * 1024
                  && ws_size >= need
                  && ((long long)n * n * n == n3l);
        if (ok) {
            int* counts  = (int*)d_ws;
            int* ovf_cnt = counts + nb;
            int* ovf     = counts + nb + 4;
            float4* binrec = (float4*)((char*)d_ws + rec_off);

            (void)hipMemsetAsync(counts, 0, (size_t)(nb + 4) * sizeof(int), stream);
            fill_recs<<<(N + block - 1) / block, block, 0, stream>>>(
                pos, cell, emb, counts, ovf_cnt, binrec, ovf, N, n);

            dim3 grid(n / 4, n);
            gather_scatter<<<grid, block, lds_bytes, stream>>>(
                binrec, counts, out, n);

            deposit_overflow<<<(N + block - 1) / block, block, 0, stream>>>(
                pos, cell, emb, ovf_cnt, ovf, out, n);
            return;
        }
    }

    // ---- fallback: interleaved atomics + transpose ----
    size_t need = (size_t)out_size * sizeof(float);
    if (C == 8 && ws_size >= need && (n3 % 4) == 0) {
        (void)hipMemsetAsync(d_ws, 0, need, stream);
        int total = N * 27;
        deposit_tsc8_ilv<<<(total + block - 1) / block, block, 0, stream>>>(
            pos, cell, emb, ws, total, n);
        int tthreads = n3 / 4;
        transpose_ilv8<<<(tthreads + block - 1) / block, block, 0, stream>>>(
            ws, out, n3);
    } else {
        (void)hipMemsetAsync(d_out, 0, (size_t)out_size * sizeof(float), stream);
        int grid = (N + block - 1) / block;
        deposit_tsc_gen<<<grid, block, 0, stream>>>(pos, cell, emb, out, N, n, C);
    }
}